// Round 2
// baseline (1458.158 us; speedup 1.0000x reference)
//
#include <hip/hip_runtime.h>
#include <math.h>

#define BB 32
#define TT 128
#define EE 128
#define HD 128
#define G4 512   // 4*H
#define NV 32000

// ---------------- Kernel A: Z0x = emb[inputs] @ W0 + b0 ----------------
// grid 512 blocks x 256 thr; each block does 8 rows of [4096 x 512]
__global__ __launch_bounds__(256) void k_embed_w0(
    const int* __restrict__ inputs, const float* __restrict__ emb,
    const float* __restrict__ W0, const float* __restrict__ b0,
    float* __restrict__ Z0x)
{
    __shared__ float xs[8][EE];
    const int r0 = blockIdx.x * 8;
    const int tid = threadIdx.x;
    for (int i = tid; i < 8 * EE; i += 256) {
        int r = i >> 7, e = i & 127;
        int tok = inputs[r0 + r];
        xs[r][e] = emb[tok * EE + e];
    }
    __syncthreads();
    const int c2 = tid * 2;
    float2 bb2 = *(const float2*)&b0[c2];
    float acc[8][2];
    #pragma unroll
    for (int r = 0; r < 8; ++r) { acc[r][0] = bb2.x; acc[r][1] = bb2.y; }
    for (int e = 0; e < EE; ++e) {
        float2 w = *(const float2*)&W0[e * G4 + c2];
        #pragma unroll
        for (int r = 0; r < 8; ++r) {
            float x = xs[r][e];
            acc[r][0] = fmaf(x, w.x, acc[r][0]);
            acc[r][1] = fmaf(x, w.y, acc[r][1]);
        }
    }
    #pragma unroll
    for (int r = 0; r < 8; ++r) {
        float2 o2; o2.x = acc[r][0]; o2.y = acc[r][1];
        *(float2*)&Z0x[(size_t)(r0 + r) * G4 + c2] = o2;
    }
}

// ---------------- Kernel B: 2-layer LSTM, one block per batch ----------------
// 32 blocks x 512 threads. Thread tid owns gate column tid (0..511).
// h0/h1/z in LDS; U0 column register-cached; W1/U1 streamed from L2.
// NO inter-block communication.
__global__ __launch_bounds__(512) void k_lstm_b(
    const float* __restrict__ Z0x,
    const float* __restrict__ U0, const float* __restrict__ W1,
    const float* __restrict__ U1, const float* __restrict__ b1,
    float* __restrict__ y)
{
    const int b = blockIdx.x;
    const int tid = threadIdx.x;

    __shared__ float h0s[HD];
    __shared__ float h1s[HD];
    __shared__ float zb[G4];

    // register-cache U0's column for this thread's gate column
    float u0c[HD];
    #pragma unroll
    for (int e = 0; e < HD; ++e) u0c[e] = U0[e * G4 + tid];

    const float b1c = b1[tid];
    const float* __restrict__ w1p = W1 + tid;
    const float* __restrict__ u1p = U1 + tid;
    const float* __restrict__ zrow = Z0x + (size_t)b * TT * G4 + tid;

    float c0 = 0.f, c1 = 0.f;   // cell states (threads 0..127)
    if (tid < HD) { h0s[tid] = 0.f; h1s[tid] = 0.f; }
    __syncthreads();

    for (int t = 0; t < TT; ++t) {
        // ---- layer 0: z0 = Z0x[b,t,:] + h0 @ U0 ----
        float acc = zrow[(size_t)t * G4];
        #pragma unroll
        for (int e = 0; e < HD; ++e) acc = fmaf(h0s[e], u0c[e], acc);
        zb[tid] = acc;
        __syncthreads();

        if (tid < HD) {
            float zi = zb[tid], zf = zb[HD + tid], zc = zb[2 * HD + tid], zo = zb[3 * HD + tid];
            float ig = 1.f / (1.f + expf(-zi));
            float fg = 1.f / (1.f + expf(-zf));
            float og = 1.f / (1.f + expf(-zo));
            c0 = fg * c0 + ig * tanhf(zc);
            h0s[tid] = og * tanhf(c0);
        }
        __syncthreads();   // h0s now holds h0_t

        // ---- layer 1: z1 = b1 + h0_t @ W1 + h1_{t-1} @ U1 ----
        float a1 = b1c;
        #pragma unroll 8
        for (int e = 0; e < HD; ++e) a1 = fmaf(h0s[e], w1p[(size_t)e * G4], a1);
        #pragma unroll 8
        for (int e = 0; e < HD; ++e) a1 = fmaf(h1s[e], u1p[(size_t)e * G4], a1);
        zb[tid] = a1;
        __syncthreads();

        if (tid < HD) {
            float zi = zb[tid], zf = zb[HD + tid], zc = zb[2 * HD + tid], zo = zb[3 * HD + tid];
            float ig = 1.f / (1.f + expf(-zi));
            float fg = 1.f / (1.f + expf(-zf));
            float og = 1.f / (1.f + expf(-zo));
            c1 = fg * c1 + ig * tanhf(zc);
            float hn = og * tanhf(c1);
            h1s[tid] = hn;
            y[(size_t)(b * TT + t) * HD + tid] = hn;
        }
        __syncthreads();
    }
}

// ---------------- Kernel C: logits = y @ Wd + bd ----------------
__global__ __launch_bounds__(256) void k_dense(
    const float* __restrict__ y, const float* __restrict__ Wd,
    const float* __restrict__ bd, float* __restrict__ out)
{
    __shared__ float ys[64 * HD];   // 32 KB
    const int r0 = blockIdx.x * 64;
    const int v0 = blockIdx.y * 128;
    const int tid = threadIdx.x;
    for (int idx = tid; idx < 64 * HD; idx += 256) ys[idx] = y[(size_t)r0 * HD + idx];
    __syncthreads();

    const int tx = tid & 31;      // 4 cols each -> 128 cols
    const int ty = tid >> 5;      // 8 rows each -> 64 rows
    const int v = v0 + tx * 4;
    float4 bd4 = *(const float4*)&bd[v];
    float acc[8][4] = {};
    const float* yrow = &ys[(ty * 8) * HD];
    #pragma unroll 4
    for (int e = 0; e < HD; ++e) {
        float4 w = *(const float4*)&Wd[(size_t)e * NV + v];
        #pragma unroll
        for (int j = 0; j < 8; ++j) {
            float yv = yrow[j * HD + e];
            acc[j][0] = fmaf(yv, w.x, acc[j][0]);
            acc[j][1] = fmaf(yv, w.y, acc[j][1]);
            acc[j][2] = fmaf(yv, w.z, acc[j][2]);
            acc[j][3] = fmaf(yv, w.w, acc[j][3]);
        }
    }
    #pragma unroll
    for (int j = 0; j < 8; ++j) {
        int rr = r0 + ty * 8 + j;
        float4 o4;
        o4.x = acc[j][0] + bd4.x;
        o4.y = acc[j][1] + bd4.y;
        o4.z = acc[j][2] + bd4.z;
        o4.w = acc[j][3] + bd4.w;
        *(float4*)&out[(size_t)rr * NV + v] = o4;
    }
}

extern "C" void kernel_launch(void* const* d_in, const int* in_sizes, int n_in,
                              void* d_out, int out_size, void* d_ws, size_t ws_size,
                              hipStream_t stream)
{
    const int*   inputs = (const int*)  d_in[0];
    const float* emb    = (const float*)d_in[1];
    const float* W0     = (const float*)d_in[2];
    const float* U0     = (const float*)d_in[3];
    const float* b0     = (const float*)d_in[4];
    const float* W1     = (const float*)d_in[5];
    const float* U1     = (const float*)d_in[6];
    const float* b1     = (const float*)d_in[7];
    const float* Wd     = (const float*)d_in[8];
    const float* bd     = (const float*)d_in[9];
    float* out = (float*)d_out;

    // scratch layout, defensive against small ws_size:
    //   Z0x: 4096x512 f32 = 8 MB; yy: 4096x128 f32 = 2 MB
    const size_t Z0X_BYTES = (size_t)8 * 1024 * 1024;
    const size_t YY_BYTES  = (size_t)2 * 1024 * 1024;
    char* ws = (char*)d_ws;
    float *Z0x, *yy;
    if (ws_size >= Z0X_BYTES + YY_BYTES + 4096) {
        Z0x = (float*)ws;
        yy  = (float*)(ws + Z0X_BYTES);
    } else {
        // stage Z0x in the tail of d_out (read only by k_lstm, which completes
        // before k_dense rewrites all of d_out). yy stays in ws.
        size_t out_bytes = (size_t)out_size * sizeof(float);
        Z0x = (float*)((char*)d_out + out_bytes - Z0X_BYTES);
        yy  = (float*)ws;
    }

    k_embed_w0<<<512, 256, 0, stream>>>(inputs, emb, W0, b0, Z0x);

    k_lstm_b<<<BB, 512, 0, stream>>>(Z0x, U0, W1, U1, b1, yy);

    k_dense<<<dim3(64, 250), 256, 0, stream>>>(yy, Wd, bd, out);
}